// Round 3
// baseline (641.703 us; speedup 1.0000x reference)
//
#include <hip/hip_runtime.h>

typedef unsigned short u16;
typedef unsigned int   u32;
typedef __attribute__((ext_vector_type(8))) short short8;
typedef __attribute__((ext_vector_type(4))) float f32x4;

#define NN 256
#define DD 128

__device__ __forceinline__ u16 f2b(float f) {
    union { float f; u32 i; } v; v.f = f;
    u32 x = v.i;
    return (u16)((x + 0x7FFFu + ((x >> 16) & 1u)) >> 16);  // RTN-even
}
__device__ __forceinline__ float b2f(u16 u) {
    union { u32 i; float f; } v; v.i = ((u32)u) << 16; return v.f;
}
__device__ __forceinline__ u32 packbf2(float a, float b) {
    return (u32)f2b(a) | ((u32)f2b(b) << 16);
}
__device__ __forceinline__ float sigm(float z) { return 1.f / (1.f + __expf(-z)); }

// ---------------------------------------------------------------------------
// Kernel 1: transpose 6 f32 weight matrices [d][h] -> bf16 [h][d]
// order in wT: 0=w_left 1=w_lgate 2=w_right 3=w_rgate 4=w_ogate 5=w_out
// ---------------------------------------------------------------------------
__global__ void k_tw(const float* w0, const float* w1, const float* w2,
                     const float* w3, const float* w4, const float* w5,
                     u16* __restrict__ out) {
    int t = blockIdx.x * 256 + threadIdx.x;   // 6*16384 elems
    int mat = t >> 14, idx = t & 16383;
    int h = idx >> 7, d = idx & 127;
    const float* src = (mat == 0) ? w0 : (mat == 1) ? w1 : (mat == 2) ? w2
                      : (mat == 3) ? w3 : (mat == 4) ? w4 : w5;
    out[mat * 16384 + h * 128 + d] = f2b(src[d * 128 + h]);
}

// ---------------------------------------------------------------------------
// Kernel 2: LayerNorm + 5 GEMMs + gating.
// Block = (b, q, ptile): 128 rows (b, p0..p0+127, q).  left/right stored bf16
// in [b, d, q, k=p] layout (k contiguous!), ogate f32 in natural [(b,i,j)][h]
// (aliases d_out).
// ---------------------------------------------------------------------------
__global__ __launch_bounds__(256)
void k_lngemm(const float* __restrict__ x,
              const float* __restrict__ ng,  const float* __restrict__ nb,
              const u16*   __restrict__ wT,
              const float* __restrict__ bL,  const float* __restrict__ bLG,
              const float* __restrict__ bR,  const float* __restrict__ bRG,
              const float* __restrict__ bOG,
              u16* __restrict__ lT, u16* __restrict__ rT, float* __restrict__ og)
{
    __shared__ uint4 xs[128 * 16];   // xn bf16, [row][chunk ^ (row&15)] 16B units
    const int tid = threadIdx.x;
    const int bx  = blockIdx.x;
    const int b   = bx >> 9;
    const int q   = (bx >> 1) & 255;
    const int p0  = (bx & 1) * 128;

    // ---- LN phase: 16 lanes per row, 16 rows per pass, 8 passes ----
    {
        const int lr = tid >> 4;   // row-within-pass 0..15
        const int c  = tid & 15;   // 8-elem chunk 0..15
        float gg[8], bbv[8];
        {
            float4 g0 = *(const float4*)(ng + c * 8);
            float4 g1 = *(const float4*)(ng + c * 8 + 4);
            float4 b0 = *(const float4*)(nb + c * 8);
            float4 b1 = *(const float4*)(nb + c * 8 + 4);
            gg[0]=g0.x; gg[1]=g0.y; gg[2]=g0.z; gg[3]=g0.w;
            gg[4]=g1.x; gg[5]=g1.y; gg[6]=g1.z; gg[7]=g1.w;
            bbv[0]=b0.x; bbv[1]=b0.y; bbv[2]=b0.z; bbv[3]=b0.w;
            bbv[4]=b1.x; bbv[5]=b1.y; bbv[6]=b1.z; bbv[7]=b1.w;
        }
#pragma unroll
        for (int pass = 0; pass < 8; ++pass) {
            const int r = pass * 16 + lr;                 // local row 0..127
            const long gRow = (long)((b * NN + p0 + r) * NN + q);
            float4 x0 = *(const float4*)(x + gRow * DD + c * 8);
            float4 x1 = *(const float4*)(x + gRow * DD + c * 8 + 4);
            float f[8] = {x0.x, x0.y, x0.z, x0.w, x1.x, x1.y, x1.z, x1.w};
            float s1 = 0.f, s2 = 0.f;
#pragma unroll
            for (int j = 0; j < 8; ++j) { s1 += f[j]; s2 += f[j] * f[j]; }
#pragma unroll
            for (int off = 1; off < 16; off <<= 1) {
                s1 += __shfl_xor(s1, off);
                s2 += __shfl_xor(s2, off);
            }
            const float mu = s1 * (1.f / 128.f);
            const float rs = rsqrtf(s2 * (1.f / 128.f) - mu * mu + 1e-5f);
            uint4 pk;
            pk.x = packbf2((f[0]-mu)*rs*gg[0]+bbv[0], (f[1]-mu)*rs*gg[1]+bbv[1]);
            pk.y = packbf2((f[2]-mu)*rs*gg[2]+bbv[2], (f[3]-mu)*rs*gg[3]+bbv[3]);
            pk.z = packbf2((f[4]-mu)*rs*gg[4]+bbv[4], (f[5]-mu)*rs*gg[5]+bbv[5]);
            pk.w = packbf2((f[6]-mu)*rs*gg[6]+bbv[6], (f[7]-mu)*rs*gg[7]+bbv[7]);
            xs[r * 16 + (c ^ lr)] = pk;                   // xor swizzle
        }
    }
    __syncthreads();

    // ---- GEMM phase: wave w owns rows w*32..w*32+31 (2 m-tiles) ----
    const int w = tid >> 6, lane = tid & 63, quad = lane >> 4, m = lane & 15;

    short8 af[2][4];
#pragma unroll
    for (int mt = 0; mt < 2; ++mt)
#pragma unroll
        for (int s = 0; s < 4; ++s) {
            const int row = w * 32 + mt * 16 + m;
            af[mt][s] = *(const short8*)(xs + row * 16 + ((s * 4 + quad) ^ m));
        }

#pragma unroll 1
    for (int nt = 0; nt < 8; ++nt) {
        const int h = nt * 16 + m;
        f32x4 acc[5][2];
        const f32x4 zero = {0.f, 0.f, 0.f, 0.f};
#pragma unroll
        for (int g5 = 0; g5 < 5; ++g5) { acc[g5][0] = zero; acc[g5][1] = zero; }

#pragma unroll
        for (int g5 = 0; g5 < 5; ++g5) {
            const u16* wp = wT + g5 * 16384 + h * 128;
#pragma unroll
            for (int s = 0; s < 4; ++s) {
                short8 bf = *(const short8*)(wp + s * 32 + quad * 8);
                acc[g5][0] = __builtin_amdgcn_mfma_f32_16x16x32_bf16(af[0][s], bf, acc[g5][0], 0, 0, 0);
                acc[g5][1] = __builtin_amdgcn_mfma_f32_16x16x32_bf16(af[1][s], bf, acc[g5][1], 0, 0, 0);
            }
        }
        const float vbl  = bL[h],  vblg = bLG[h];
        const float vbr  = bR[h],  vbrg = bRG[h];
        const float vbog = bOG[h];
#pragma unroll
        for (int mt = 0; mt < 2; ++mt) {
            const int pl = w * 32 + mt * 16 + quad * 4;   // local p base (4 consecutive)
            u16 lp[4], rp[4];
#pragma unroll
            for (int rg = 0; rg < 4; ++rg) {
                float lv = (acc[0][mt][rg] + vbl) * sigm(acc[1][mt][rg] + vblg);
                float rv = (acc[2][mt][rg] + vbr) * sigm(acc[3][mt][rg] + vbrg);
                float ov = sigm(acc[4][mt][rg] + vbog);
                lp[rg] = f2b(lv); rp[rg] = f2b(rv);
                const int p = p0 + pl + rg;
                og[((long)((b * NN + p) * NN + q)) * DD + h] = ov;   // f32
            }
            const long tbase = ((long)((b * DD + h) * NN + q)) * NN + p0 + pl;
            *(uint2*)(lT + tbase) = *(uint2*)lp;
            *(uint2*)(rT + tbase) = *(uint2*)rp;
        }
    }
}

// ---------------------------------------------------------------------------
// Kernel 3: mix.  Per (b,d): C[i,j] = sum_k right[k,i]*left[k,j], both stored
// bf16 [b,d,q,k] so A/B fragments are direct 16B global loads.  Block tile
// 128x128, wave tile 64x64.  Output mx bf16 in [b,d,i,j].
// ---------------------------------------------------------------------------
__global__ __launch_bounds__(256)
void k_mix(const u16* __restrict__ lT, const u16* __restrict__ rT,
           u16* __restrict__ mx)
{
    const int tid = threadIdx.x;
    const int bx  = blockIdx.x;
    const int bd  = bx >> 2;               // b*128 + d
    const int it  = (bx >> 1) & 1, jt = bx & 1;
    const int w = tid >> 6, lane = tid & 63, quad = lane >> 4, m = lane & 15;
    const int ib = it * 128 + (w >> 1) * 64;
    const int jb = jt * 128 + (w & 1) * 64;

    const u16* A  = rT + (long)bd * 65536;   // right: A[i][k]
    const u16* Bp = lT + (long)bd * 65536;   // left : B[k][j] (j-major, k-fastest)

    f32x4 acc[4][4];
    const f32x4 zero = {0.f, 0.f, 0.f, 0.f};
#pragma unroll
    for (int a = 0; a < 4; ++a)
#pragma unroll
        for (int c = 0; c < 4; ++c) acc[a][c] = zero;

#pragma unroll 1
    for (int kc = 0; kc < 8; ++kc) {
        short8 afr[4], bfr[4];
#pragma unroll
        for (int tI = 0; tI < 4; ++tI)
            afr[tI] = *(const short8*)(A + (ib + tI * 16 + m) * 256 + kc * 32 + quad * 8);
#pragma unroll
        for (int tJ = 0; tJ < 4; ++tJ)
            bfr[tJ] = *(const short8*)(Bp + (jb + tJ * 16 + m) * 256 + kc * 32 + quad * 8);
#pragma unroll
        for (int tI = 0; tI < 4; ++tI)
#pragma unroll
            for (int tJ = 0; tJ < 4; ++tJ)
                acc[tI][tJ] = __builtin_amdgcn_mfma_f32_16x16x32_bf16(afr[tI], bfr[tJ], acc[tI][tJ], 0, 0, 0);
    }

#pragma unroll
    for (int tI = 0; tI < 4; ++tI)
#pragma unroll
        for (int tJ = 0; tJ < 4; ++tJ) {
            const int j = jb + tJ * 16 + m;
#pragma unroll
            for (int rg = 0; rg < 4; ++rg) {
                const int i = ib + tI * 16 + quad * 4 + rg;
                mx[(long)bd * 65536 + i * 256 + j] = f2b(acc[tI][tJ][rg]);
            }
        }
}

// ---------------------------------------------------------------------------
// Kernel 4: final.  Block = (b, i, j-tile of 64).  Loads mx[b,:,i,j0:j0+64]
// (coalesced per d-row), LN over d per j, * ogate (f32), then y @ w_outT +
// b_out -> f32 out.  og aliases out: each block reads only its own rows
// before overwriting them (disjoint across blocks).
// ---------------------------------------------------------------------------
__global__ __launch_bounds__(256)
void k_final(const u16* __restrict__ mx, const float* __restrict__ og,
             const u16* __restrict__ wT5, const float* __restrict__ ong,
             const float* __restrict__ onb, const float* __restrict__ bo_,
             float* __restrict__ out)
{
    __shared__ uint4 m1[128 * 9];    // [d][jchunk] (8 data + 1 pad) bf16
    __shared__ uint4 ys[64 * 16];    // [j][chunk ^ (j&15)] bf16 (A-frag layout)
    __shared__ float mu_s[64], rs_s[64];

    const int tid = threadIdx.x;
    const int bx  = blockIdx.x;
    const int b   = bx >> 10;
    const int i   = (bx >> 2) & 255;
    const int j0  = (bx & 3) * 64;
    const long base = ((long)b * 128) * 65536 + (long)i * 256 + j0;

    {   // load mixed tile: 128 d-rows x 64 j (bf16)
        const int dr = tid >> 3, cc = tid & 7;
#pragma unroll
        for (int pass = 0; pass < 4; ++pass) {
            const int d = pass * 32 + dr;
            m1[d * 9 + cc] = *(const uint4*)(mx + base + (long)d * 65536 + cc * 8);
        }
    }
    __syncthreads();

    if (tid < 128) {   // stats: 2 threads per j
        const int j = tid >> 1, half = tid & 1;
        float s1 = 0.f, s2 = 0.f;
        for (int d = half * 64; d < half * 64 + 64; ++d) {
            float v = b2f(((const u16*)(m1 + d * 9))[j]);
            s1 += v; s2 += v * v;
        }
        s1 += __shfl_xor(s1, 1); s2 += __shfl_xor(s2, 1);
        if (half == 0) {
            const float mu = s1 * (1.f / 128.f);
            mu_s[j] = mu;
            rs_s[j] = rsqrtf(s2 * (1.f / 128.f) - mu * mu + 1e-5f);
        }
    }
    __syncthreads();

    {   // y = (LN(mixed) * ogate) staged bf16 in A-frag layout
        const int j = tid >> 2, c2 = tid & 3;
        const float mu = mu_s[j], rs = rs_s[j];
        const long orow = ((long)((b * NN + i) * NN + j0 + j)) * DD;
#pragma unroll
        for (int s4 = 0; s4 < 4; ++s4) {
            const int ch = c2 * 4 + s4;          // d chunk 0..15
            float4 o0 = *(const float4*)(og + orow + ch * 8);
            float4 o1 = *(const float4*)(og + orow + ch * 8 + 4);
            float4 g0 = *(const float4*)(ong + ch * 8);
            float4 g1 = *(const float4*)(ong + ch * 8 + 4);
            float4 n0 = *(const float4*)(onb + ch * 8);
            float4 n1 = *(const float4*)(onb + ch * 8 + 4);
            float ov[8] = {o0.x,o0.y,o0.z,o0.w,o1.x,o1.y,o1.z,o1.w};
            float gv[8] = {g0.x,g0.y,g0.z,g0.w,g1.x,g1.y,g1.z,g1.w};
            float bv[8] = {n0.x,n0.y,n0.z,n0.w,n1.x,n1.y,n1.z,n1.w};
            u16 yy[8];
#pragma unroll
            for (int jj = 0; jj < 8; ++jj) {
                const int d = ch * 8 + jj;
                const float v = b2f(((const u16*)(m1 + d * 9))[j]);
                yy[jj] = f2b(((v - mu) * rs * gv[jj] + bv[jj]) * ov[jj]);
            }
            ys[j * 16 + (ch ^ (j & 15))] = *(uint4*)yy;
        }
    }
    __syncthreads();

    // GEMM: 64 j-rows x 128 e, K = 128.  wave w -> m-tile w.
    const int w = tid >> 6, lane = tid & 63, quad = lane >> 4, m = lane & 15;
    short8 afr[4];
#pragma unroll
    for (int s = 0; s < 4; ++s)
        afr[s] = *(const short8*)(ys + (w * 16 + m) * 16 + ((s * 4 + quad) ^ m));

#pragma unroll 1
    for (int et = 0; et < 8; ++et) {
        f32x4 acc = {0.f, 0.f, 0.f, 0.f};
        const u16* wp = wT5 + (et * 16 + m) * 128;
#pragma unroll
        for (int s = 0; s < 4; ++s) {
            short8 bfr = *(const short8*)(wp + s * 32 + quad * 8);
            acc = __builtin_amdgcn_mfma_f32_16x16x32_bf16(afr[s], bfr, acc, 0, 0, 0);
        }
        const int e = et * 16 + m;
        const float bo = bo_[e];
#pragma unroll
        for (int rg = 0; rg < 4; ++rg) {
            const int j = j0 + w * 16 + quad * 4 + rg;
            out[((long)((b * NN + i) * NN + j)) * DD + e] = acc[rg] + bo;   // f32
        }
    }
}

// ---------------------------------------------------------------------------
extern "C" void kernel_launch(void* const* d_in, const int* in_sizes, int n_in,
                              void* d_out, int out_size, void* d_ws, size_t ws_size,
                              hipStream_t stream) {
    const float* x   = (const float*)d_in[0];
    const float* ng  = (const float*)d_in[1];
    const float* nb  = (const float*)d_in[2];
    const float* wl  = (const float*)d_in[3];
    const float* bl  = (const float*)d_in[4];
    const float* wr  = (const float*)d_in[5];
    const float* br  = (const float*)d_in[6];
    const float* wlg = (const float*)d_in[7];
    const float* blg = (const float*)d_in[8];
    const float* wrg = (const float*)d_in[9];
    const float* brg = (const float*)d_in[10];
    const float* wog = (const float*)d_in[11];
    const float* bog = (const float*)d_in[12];
    const float* ong = (const float*)d_in[13];
    const float* onb = (const float*)d_in[14];
    const float* wo  = (const float*)d_in[15];
    const float* bo  = (const float*)d_in[16];

    u16* ws = (u16*)d_ws;
    const long BIG = 33554432;          // 4*128*256*256 elements
    // Workspace: lT, rT, mx (bf16, 3 x 64 MiB) + 192 KiB bf16 weights.
    // og (f32) aliases d_out: k_lngemm writes it, k_final reads each block's
    // own rows before overwriting them with the f32 output.
    const size_t need = (size_t)(3 * BIG + 6 * 16384) * sizeof(u16);
    if (ws_size < need) return;  // clean failure instead of OOB fault

    u16* lT = ws;                        // bf16 [b,d,q,k]
    u16* rT = lT + BIG;                  // bf16 [b,d,q,k]
    u16* mx = rT + BIG;                  // bf16 [b,d,i,j]
    u16* wT = mx + BIG;                  // bf16, 6 x 128x128 transposed weights
    float* og = (float*)d_out;           // f32 [(b,i,j)][h]  (aliases d_out)

    k_tw<<<384, 256, 0, stream>>>(wl, wlg, wr, wrg, wog, wo, wT);
    k_lngemm<<<2048, 256, 0, stream>>>(x, ng, nb, wT, bl, blg, br, brg, bog, lT, rT, og);
    k_mix<<<2048, 256, 0, stream>>>(lT, rT, mx);
    k_final<<<4096, 256, 0, stream>>>(mx, og, wT + 5 * 16384, ong, onb, bo, (float*)d_out);
}